// Round 1
// baseline (182.773 us; speedup 1.0000x reference)
//
#include <hip/hip_runtime.h>

// BertEmbedding: masked segment-mean pooling + linear projection
// B=64, S=512, H=768, E=512, T=256
// out[b,t,e] = (t<len_b ? segmean_{s: wid[b,s]=t} hidden[b,s,:] : 0) . W[e,:] + bias[e]

#define B_N   64
#define S_LEN 512
#define H_DIM 768
#define E_DIM 512
#define T_SEG 256
#define M_TOT (B_N * T_SEG)   // 16384

typedef unsigned short u16;
typedef __bf16 bf16x8 __attribute__((ext_vector_type(8)));
typedef float f32x4 __attribute__((ext_vector_type(4)));

// RNE float->bf16 (finite inputs only)
__device__ __forceinline__ u16 f2bf(float x) {
    union { float f; unsigned int u; } v; v.f = x;
    unsigned int r = (v.u + 0x7fffu + ((v.u >> 16) & 1u)) >> 16;
    return (u16)r;
}

// ---------------------------------------------------------------------------
// Kernel 1: per-batch segment boundaries. word_ids sorted -> each segment is
// contiguous; histogram + exclusive scan gives (start, count) per (b, t).
__global__ __launch_bounds__(256) void seg_bounds_kernel(
    const int* __restrict__ wid, int* __restrict__ starts, int* __restrict__ counts) {
    __shared__ int cnt[T_SEG];
    const int b = blockIdx.x;
    const int tid = threadIdx.x;
    cnt[tid] = 0;
    __syncthreads();
    for (int s = tid; s < S_LEN; s += 256)
        atomicAdd(&cnt[wid[b * S_LEN + s]], 1);
    __syncthreads();
    const int v = cnt[tid];
    // Hillis-Steele inclusive scan in LDS
    for (int off = 1; off < T_SEG; off <<= 1) {
        int t = 0;
        if (tid >= off) t = cnt[tid - off];
        __syncthreads();
        cnt[tid] += t;
        __syncthreads();
    }
    const int incl = cnt[tid];
    starts[b * T_SEG + tid] = incl - v;
    counts[b * T_SEG + tid] = v;
}

// ---------------------------------------------------------------------------
// Kernel 2: W fp32 -> bf16
__global__ __launch_bounds__(256) void wconv_kernel(
    const float* __restrict__ W, u16* __restrict__ Wbf) {
    const int i = (blockIdx.x * 256 + threadIdx.x) * 4;
    const float4 f = *reinterpret_cast<const float4*>(W + i);
    ushort4 u;
    u.x = f2bf(f.x); u.y = f2bf(f.y); u.z = f2bf(f.z); u.w = f2bf(f.w);
    *reinterpret_cast<ushort4*>(Wbf + i) = u;
}

// ---------------------------------------------------------------------------
// Kernel 3: segment-mean pooling -> pooled[M_TOT][H_DIM] bf16.
// One block per (b, t); threads stride H (768 = 3*256). Masked / empty rows
// write zeros (d_ws is poisoned, so every element must be written).
__global__ __launch_bounds__(256) void pool_kernel(
    const float* __restrict__ hidden, const int* __restrict__ tlen,
    const int* __restrict__ starts, const int* __restrict__ counts,
    u16* __restrict__ pooled) {
    const int t = blockIdx.x, b = blockIdx.y, tid = threadIdx.x;
    const int idx = b * T_SEG + t;
    const int cnt = counts[idx];
    const int st  = starts[idx];
    const bool live = (t < tlen[b]) && (cnt > 0);
    float a0 = 0.f, a1 = 0.f, a2 = 0.f;
    if (live) {
        const float* base = hidden + (size_t)(b * S_LEN + st) * H_DIM;
        for (int s = 0; s < cnt; ++s) {
            a0 += base[tid];
            a1 += base[tid + 256];
            a2 += base[tid + 512];
            base += H_DIM;
        }
        const float inv = 1.0f / (float)cnt;
        a0 *= inv; a1 *= inv; a2 *= inv;
    }
    u16* o = pooled + (size_t)idx * H_DIM;
    o[tid]       = f2bf(a0);
    o[tid + 256] = f2bf(a1);
    o[tid + 512] = f2bf(a2);
}

// ---------------------------------------------------------------------------
// Kernel 4: C[m][n] = sum_k A[m][k] * Bm[n][k] + bias[n]
// A = pooled [M=16384, K=768] bf16 row-major, Bm = W [N=512, K=768] bf16
// (K-major: a B^T GEMM). 128x128 tile, BK=64, 256 threads = 4 waves in 2x2,
// each wave 4x4 grid of 16x16x32 MFMAs. global_load_lds width=16 staging.
__global__ __launch_bounds__(256) void gemm_bt_kernel(
    const u16* __restrict__ A, const u16* __restrict__ Bm,
    const float* __restrict__ bias, float* __restrict__ C) {
    constexpr int BM = 128, BN = 128, BK = 64, K = H_DIM, N = E_DIM;
    __shared__ u16 lA[BM * BK];   // 16 KB, row-major [BM][BK]
    __shared__ u16 lB[BN * BK];   // 16 KB

    const int tid  = threadIdx.x;
    const int wave = tid >> 6;
    const int lane = tid & 63;
    const int wm = wave >> 1, wn = wave & 1;   // 2x2 waves -> 64x64 each
    const int m0 = blockIdx.x * BM;
    const int n0 = blockIdx.y * BN;

    // staging: 16 chunks of 1024B per tile (8 rows x 128B); wave handles 4.
    // lane l -> row c*8 + l/8, col (l%8)*8; lands at LDS chunk base + l*16.
    const int lrow = lane >> 3;
    const int lcol = (lane & 7) * 8;

    f32x4 acc[4][4] = {};

    for (int k0 = 0; k0 < K; k0 += BK) {
#pragma unroll
        for (int i = 0; i < 4; ++i) {
            const int c = wave * 4 + i;
            const int row = c * 8 + lrow;
            const u16* ga = A  + (size_t)(m0 + row) * K + k0 + lcol;
            const u16* gb = Bm + (size_t)(n0 + row) * K + k0 + lcol;
            __builtin_amdgcn_global_load_lds(
                (const __attribute__((address_space(1))) void*)ga,
                (__attribute__((address_space(3))) void*)(lA + c * 512), 16, 0, 0);
            __builtin_amdgcn_global_load_lds(
                (const __attribute__((address_space(1))) void*)gb,
                (__attribute__((address_space(3))) void*)(lB + c * 512), 16, 0, 0);
        }
        __syncthreads();

#pragma unroll
        for (int kt = 0; kt < 2; ++kt) {
            const int ko = kt * 32 + (lane >> 4) * 8;
            bf16x8 af[4], bfv[4];
#pragma unroll
            for (int i = 0; i < 4; ++i) {
                const int ar = wm * 64 + i * 16 + (lane & 15);
                af[i]  = *reinterpret_cast<const bf16x8*>(lA + ar * BK + ko);
                const int br = wn * 64 + i * 16 + (lane & 15);
                bfv[i] = *reinterpret_cast<const bf16x8*>(lB + br * BK + ko);
            }
#pragma unroll
            for (int mi = 0; mi < 4; ++mi)
#pragma unroll
                for (int ni = 0; ni < 4; ++ni)
                    acc[mi][ni] = __builtin_amdgcn_mfma_f32_16x16x32_bf16(
                        af[mi], bfv[ni], acc[mi][ni], 0, 0, 0);
        }
        __syncthreads();
    }

    // epilogue: C/D layout col = lane&15, row = (lane>>4)*4 + reg
    const int cn = lane & 15;
    const int rq = (lane >> 4) * 4;
#pragma unroll
    for (int ni = 0; ni < 4; ++ni) {
        const int gn = n0 + wn * 64 + ni * 16 + cn;
        const float bv = bias[gn];
#pragma unroll
        for (int mi = 0; mi < 4; ++mi) {
            const int gmb = m0 + wm * 64 + mi * 16 + rq;
#pragma unroll
            for (int r = 0; r < 4; ++r)
                C[(size_t)(gmb + r) * N + gn] = acc[mi][ni][r] + bv;
        }
    }
}

// ---------------------------------------------------------------------------
extern "C" void kernel_launch(void* const* d_in, const int* in_sizes, int n_in,
                              void* d_out, int out_size, void* d_ws, size_t ws_size,
                              hipStream_t stream) {
    const float* hidden = (const float*)d_in[0];
    const int*   wid    = (const int*)d_in[1];
    const int*   tlen   = (const int*)d_in[2];
    const float* W      = (const float*)d_in[3];
    const float* bias   = (const float*)d_in[4];
    float* out = (float*)d_out;

    // workspace layout (all offsets 16B-aligned)
    constexpr size_t POOLED_BYTES = (size_t)M_TOT * H_DIM * 2;   // 25,165,824
    constexpr size_t WBF_BYTES    = (size_t)E_DIM * H_DIM * 2;   //    786,432
    constexpr size_t SC_BYTES     = (size_t)B_N * T_SEG * 4;     //     65,536
    char* ws = (char*)d_ws;
    u16* pooled = (u16*)ws;
    u16* wbf    = (u16*)(ws + POOLED_BYTES);
    int* starts = (int*)(ws + POOLED_BYTES + WBF_BYTES);
    int* counts = (int*)(ws + POOLED_BYTES + WBF_BYTES + SC_BYTES);

    seg_bounds_kernel<<<B_N, 256, 0, stream>>>(wid, starts, counts);
    wconv_kernel<<<(E_DIM * H_DIM) / 1024, 256, 0, stream>>>(W, wbf);
    pool_kernel<<<dim3(T_SEG, B_N), 256, 0, stream>>>(hidden, tlen, starts, counts, pooled);
    gemm_bt_kernel<<<dim3(M_TOT / 128, E_DIM / 128), 256, 0, stream>>>(pooled, wbf, bias, out);
}

// Round 2
// 177.393 us; speedup vs baseline: 1.0303x; 1.0303x over previous
//
#include <hip/hip_runtime.h>

// BertEmbedding: masked segment-mean pooling + linear projection
// B=64, S=512, H=768, E=512, T=256
// out[b,t,e] = (t<len_b ? segmean_{s: wid[b,s]=t} hidden[b,s,:] : 0) . W[e,:] + bias[e]

#define B_N   64
#define S_LEN 512
#define H_DIM 768
#define E_DIM 512
#define T_SEG 256
#define M_TOT (B_N * T_SEG)   // 16384

typedef unsigned short u16;
typedef __bf16 bf16x8 __attribute__((ext_vector_type(8)));
typedef float f32x4 __attribute__((ext_vector_type(4)));

// RNE float->bf16 (finite inputs only)
__device__ __forceinline__ u16 f2bf(float x) {
    union { float f; unsigned int u; } v; v.f = x;
    unsigned int r = (v.u + 0x7fffu + ((v.u >> 16) & 1u)) >> 16;
    return (u16)r;
}

// ---------------------------------------------------------------------------
// Kernel 1 (fused prep):
//   blocks [0, 384):   W fp32 -> bf16 (float4 per thread)
//   blocks [384, 448): per-batch segment boundaries (histogram + scan)
__global__ __launch_bounds__(256) void prep_kernel(
    const float* __restrict__ W, u16* __restrict__ Wbf,
    const int* __restrict__ wid, int* __restrict__ starts, int* __restrict__ counts) {
    __shared__ int cnt[T_SEG];
    const int tid = threadIdx.x;
    if (blockIdx.x < 384) {
        const int i = (blockIdx.x * 256 + tid) * 4;
        const float4 f = *reinterpret_cast<const float4*>(W + i);
        ushort4 u;
        u.x = f2bf(f.x); u.y = f2bf(f.y); u.z = f2bf(f.z); u.w = f2bf(f.w);
        *reinterpret_cast<ushort4*>(Wbf + i) = u;
        return;
    }
    const int b = blockIdx.x - 384;
    cnt[tid] = 0;
    __syncthreads();
    // word_ids sorted per batch -> segments contiguous; histogram then scan
    {
        const int s0 = wid[b * S_LEN + tid];
        const int s1 = wid[b * S_LEN + 256 + tid];
        atomicAdd(&cnt[s0], 1);
        atomicAdd(&cnt[s1], 1);
    }
    __syncthreads();
    const int v = cnt[tid];
    // Hillis-Steele inclusive scan in LDS
    for (int off = 1; off < T_SEG; off <<= 1) {
        int t = 0;
        if (tid >= off) t = cnt[tid - off];
        __syncthreads();
        cnt[tid] += t;
        __syncthreads();
    }
    starts[b * T_SEG + tid] = cnt[tid] - v;
    counts[b * T_SEG + tid] = v;
}

// ---------------------------------------------------------------------------
// Kernel 2: segment-mean pooling -> pooled[M_TOT][H_DIM] bf16.
// One block per (b, t); 192 threads (3 waves), one float4 per thread per row.
// Segment loop unrolled x2 with independent accumulators for ILP.
// Masked / empty rows write zeros (d_ws is poisoned -> must write everything).
__global__ __launch_bounds__(192) void pool_kernel(
    const float* __restrict__ hidden, const int* __restrict__ tlen,
    const int* __restrict__ starts, const int* __restrict__ counts,
    u16* __restrict__ pooled) {
    const int t = blockIdx.x, b = blockIdx.y, tid = threadIdx.x;
    const int idx = b * T_SEG + t;
    const int cnt = counts[idx];
    const int st  = starts[idx];
    const bool live = (t < tlen[b]) && (cnt > 0);
    f32x4 a0 = {0.f, 0.f, 0.f, 0.f}, a1 = {0.f, 0.f, 0.f, 0.f};
    if (live) {
        const f32x4* base = reinterpret_cast<const f32x4*>(
            hidden + (size_t)(b * S_LEN + st) * H_DIM) + tid;
        int s = 0;
        for (; s + 2 <= cnt; s += 2) {
            a0 += base[0];
            a1 += base[192];
            base += 384;
        }
        if (s < cnt) a0 += base[0];
        a0 += a1;
        const float inv = 1.0f / (float)cnt;
        a0 *= inv;
    }
    ushort4 u;
    u.x = f2bf(a0[0]); u.y = f2bf(a0[1]); u.z = f2bf(a0[2]); u.w = f2bf(a0[3]);
    *reinterpret_cast<ushort4*>(pooled + (size_t)idx * H_DIM + tid * 4) = u;
}

// ---------------------------------------------------------------------------
// Kernel 3: C[m][n] = sum_k A[m][k] * Bm[n][k] + bias[n]
// A = pooled [M=16384, K=768] bf16 row-major, Bm = W [N=512, K=768] bf16
// (K-major: a B^T GEMM). 128x128 tile, BK=64, 256 threads = 4 waves in 2x2,
// each wave 4x4 grid of 16x16x32 MFMAs. global_load_lds width=16 staging.
__global__ __launch_bounds__(256) void gemm_bt_kernel(
    const u16* __restrict__ A, const u16* __restrict__ Bm,
    const float* __restrict__ bias, float* __restrict__ C) {
    constexpr int BM = 128, BN = 128, BK = 64, K = H_DIM, N = E_DIM;
    __shared__ u16 lA[BM * BK];   // 16 KB, row-major [BM][BK]
    __shared__ u16 lB[BN * BK];   // 16 KB

    const int tid  = threadIdx.x;
    const int wave = tid >> 6;
    const int lane = tid & 63;
    const int wm = wave >> 1, wn = wave & 1;   // 2x2 waves -> 64x64 each
    const int m0 = blockIdx.x * BM;
    const int n0 = blockIdx.y * BN;

    // staging: 16 chunks of 1024B per tile (8 rows x 128B); wave handles 4.
    // lane l -> row c*8 + l/8, col (l%8)*8; lands at LDS chunk base + l*16.
    const int lrow = lane >> 3;
    const int lcol = (lane & 7) * 8;

    f32x4 acc[4][4] = {};

    for (int k0 = 0; k0 < K; k0 += BK) {
#pragma unroll
        for (int i = 0; i < 4; ++i) {
            const int c = wave * 4 + i;
            const int row = c * 8 + lrow;
            const u16* ga = A  + (size_t)(m0 + row) * K + k0 + lcol;
            const u16* gb = Bm + (size_t)(n0 + row) * K + k0 + lcol;
            __builtin_amdgcn_global_load_lds(
                (const __attribute__((address_space(1))) void*)ga,
                (__attribute__((address_space(3))) void*)(lA + c * 512), 16, 0, 0);
            __builtin_amdgcn_global_load_lds(
                (const __attribute__((address_space(1))) void*)gb,
                (__attribute__((address_space(3))) void*)(lB + c * 512), 16, 0, 0);
        }
        __syncthreads();

#pragma unroll
        for (int kt = 0; kt < 2; ++kt) {
            const int ko = kt * 32 + (lane >> 4) * 8;
            bf16x8 af[4], bfv[4];
#pragma unroll
            for (int i = 0; i < 4; ++i) {
                const int ar = wm * 64 + i * 16 + (lane & 15);
                af[i]  = *reinterpret_cast<const bf16x8*>(lA + ar * BK + ko);
                const int br = wn * 64 + i * 16 + (lane & 15);
                bfv[i] = *reinterpret_cast<const bf16x8*>(lB + br * BK + ko);
            }
#pragma unroll
            for (int mi = 0; mi < 4; ++mi)
#pragma unroll
                for (int ni = 0; ni < 4; ++ni)
                    acc[mi][ni] = __builtin_amdgcn_mfma_f32_16x16x32_bf16(
                        af[mi], bfv[ni], acc[mi][ni], 0, 0, 0);
        }
        __syncthreads();
    }

    // epilogue: C/D layout col = lane&15, row = (lane>>4)*4 + reg
    const int cn = lane & 15;
    const int rq = (lane >> 4) * 4;
#pragma unroll
    for (int ni = 0; ni < 4; ++ni) {
        const int gn = n0 + wn * 64 + ni * 16 + cn;
        const float bv = bias[gn];
#pragma unroll
        for (int mi = 0; mi < 4; ++mi) {
            const int gmb = m0 + wm * 64 + mi * 16 + rq;
#pragma unroll
            for (int r = 0; r < 4; ++r)
                C[(size_t)(gmb + r) * N + gn] = acc[mi][ni][r] + bv;
        }
    }
}

// ---------------------------------------------------------------------------
extern "C" void kernel_launch(void* const* d_in, const int* in_sizes, int n_in,
                              void* d_out, int out_size, void* d_ws, size_t ws_size,
                              hipStream_t stream) {
    const float* hidden = (const float*)d_in[0];
    const int*   wid    = (const int*)d_in[1];
    const int*   tlen   = (const int*)d_in[2];
    const float* W      = (const float*)d_in[3];
    const float* bias   = (const float*)d_in[4];
    float* out = (float*)d_out;

    // workspace layout (all offsets 16B-aligned)
    constexpr size_t POOLED_BYTES = (size_t)M_TOT * H_DIM * 2;   // 25,165,824
    constexpr size_t WBF_BYTES    = (size_t)E_DIM * H_DIM * 2;   //    786,432
    constexpr size_t SC_BYTES     = (size_t)B_N * T_SEG * 4;     //     65,536
    char* ws = (char*)d_ws;
    u16* pooled = (u16*)ws;
    u16* wbf    = (u16*)(ws + POOLED_BYTES);
    int* starts = (int*)(ws + POOLED_BYTES + WBF_BYTES);
    int* counts = (int*)(ws + POOLED_BYTES + WBF_BYTES + SC_BYTES);

    prep_kernel<<<448, 256, 0, stream>>>(W, wbf, wid, starts, counts);
    pool_kernel<<<dim3(T_SEG, B_N), 192, 0, stream>>>(hidden, tlen, starts, counts, pooled);
    gemm_bt_kernel<<<dim3(M_TOT / 128, E_DIM / 128), 256, 0, stream>>>(pooled, wbf, bias, out);
}

// Round 3
// 172.602 us; speedup vs baseline: 1.0589x; 1.0278x over previous
//
#include <hip/hip_runtime.h>

// BertEmbedding: masked segment-mean pooling + linear projection
// B=64, S=512, H=768, E=512, T=256
// out[b,t,e] = (t<len_b ? segmean_{s: wid[b,s]=t} hidden[b,s,:] : 0) . W[e,:] + bias[e]
//
// Structure (2 dispatches):
//  K1 pool_or_wconv: blocks [0,16384) pool one (b,t) each, computing segment
//     bounds inline via ballot-reduction over L2-cached wid[b,:]; blocks
//     [16384,16768) convert W fp32->bf16. One dispatch -> concurrent.
//  K2 gemm_bt: m97-style 128x128/BK=64 bf16 MFMA GEMM, bias fused; tiles that
//     are fully masked (t0 >= tlen[b]) skip straight to a coalesced bias write.

#define B_N   64
#define S_LEN 512
#define H_DIM 768
#define E_DIM 512
#define T_SEG 256
#define M_TOT (B_N * T_SEG)   // 16384
#define POOL_BLOCKS M_TOT
#define WCONV_BLOCKS ((E_DIM * H_DIM) / 1024)   // 384

typedef unsigned short u16;
typedef __bf16 bf16x8 __attribute__((ext_vector_type(8)));
typedef float f32x4 __attribute__((ext_vector_type(4)));

// RNE float->bf16 (finite inputs only)
__device__ __forceinline__ u16 f2bf(float x) {
    union { float f; unsigned int u; } v; v.f = x;
    unsigned int r = (v.u + 0x7fffu + ((v.u >> 16) & 1u)) >> 16;
    return (u16)r;
}

// ---------------------------------------------------------------------------
// Kernel 1: pooling (+ inline segment bounds) and W conversion in one grid.
__global__ __launch_bounds__(256) void pool_or_wconv_kernel(
    const float* __restrict__ hidden, const int* __restrict__ wid,
    const int* __restrict__ tlen, const float* __restrict__ W,
    u16* __restrict__ wbf, u16* __restrict__ pooled) {
    const int tid = threadIdx.x;

    if (blockIdx.x >= POOL_BLOCKS) {
        // ---- W fp32 -> bf16, float4 per thread ----
        const int i = ((blockIdx.x - POOL_BLOCKS) * 256 + tid) * 4;
        const float4 f = *reinterpret_cast<const float4*>(W + i);
        ushort4 u;
        u.x = f2bf(f.x); u.y = f2bf(f.y); u.z = f2bf(f.z); u.w = f2bf(f.w);
        *reinterpret_cast<ushort4*>(wbf + i) = u;
        return;
    }

    // ---- pooling for one (b, t) ----
    const int b = blockIdx.x >> 8;
    const int t = blockIdx.x & 255;
    const int tl = tlen[b];

    // Rows with t >= 128 whose whole GEMM tile is masked (tl <= 128) are never
    // read by the GEMM (it early-exits to bias) -> skip entirely.
    if (t >= 128 && tl <= 128) return;

    // segment bounds via ballot: wid[b,:] is sorted; start = #(wid < t),
    // cnt = #(wid == t). 256 threads x 2 values cover S=512.
    const int w0 = wid[b * S_LEN + tid];
    const int w1 = wid[b * S_LEN + 256 + tid];
    const unsigned long long blt0 = __ballot(w0 < t);
    const unsigned long long blt1 = __ballot(w1 < t);
    const unsigned long long beq0 = __ballot(w0 == t);
    const unsigned long long beq1 = __ballot(w1 == t);
    __shared__ int red[8];
    const int wave = tid >> 6, lane = tid & 63;
    if (lane == 0) {
        red[wave]     = __popcll(blt0) + __popcll(blt1);
        red[4 + wave] = __popcll(beq0) + __popcll(beq1);
    }
    __syncthreads();
    const int st  = red[0] + red[1] + red[2] + red[3];
    const int cnt = red[4] + red[5] + red[6] + red[7];

    const bool live = (t < tl) && (cnt > 0);
    f32x4 a0 = {0.f, 0.f, 0.f, 0.f}, a1 = {0.f, 0.f, 0.f, 0.f};
    if (live && tid < 192) {   // 192 lanes x float4 = 768 floats = one row
        const f32x4* base = reinterpret_cast<const f32x4*>(
            hidden + (size_t)(b * S_LEN + st) * H_DIM) + tid;
        int s = 0;
        for (; s + 2 <= cnt; s += 2) {
            a0 += base[0];
            a1 += base[192];
            base += 384;
        }
        if (s < cnt) a0 += base[0];
        a0 += a1;
        const float inv = 1.0f / (float)cnt;
        a0 *= inv;
    }
    if (tid < 192) {
        ushort4 u;
        u.x = f2bf(a0[0]); u.y = f2bf(a0[1]); u.z = f2bf(a0[2]); u.w = f2bf(a0[3]);
        *reinterpret_cast<ushort4*>(
            pooled + (size_t)(blockIdx.x) * H_DIM + tid * 4) = u;
    }
}

// ---------------------------------------------------------------------------
// Kernel 2: C[m][n] = sum_k A[m][k] * Bm[n][k] + bias[n]
// A = pooled [M=16384, K=768] bf16 row-major, Bm = W [N=512, K=768] bf16
// (K-major: a B^T GEMM). 128x128 tile, BK=64, 256 threads = 4 waves in 2x2,
// each wave 4x4 grid of 16x16x32 MFMAs. global_load_lds width=16 staging.
// Fully-masked tiles (t0 >= tlen[b]) write bias only.
__global__ __launch_bounds__(256) void gemm_bt_kernel(
    const u16* __restrict__ A, const u16* __restrict__ Bm,
    const float* __restrict__ bias, const int* __restrict__ tlen,
    float* __restrict__ C) {
    constexpr int BM = 128, BN = 128, BK = 64, K = H_DIM, N = E_DIM;
    __shared__ u16 lA[BM * BK];   // 16 KB, row-major [BM][BK]
    __shared__ u16 lB[BN * BK];   // 16 KB

    const int tid  = threadIdx.x;
    const int m0 = blockIdx.x * BM;
    const int n0 = blockIdx.y * BN;

    // ---- fully-masked tile: out = bias, coalesced float4 writes ----
    const int bb = m0 >> 8;          // batch of this m-tile (256 rows/batch)
    const int t0 = m0 & 255;         // tile start within batch
    if (t0 >= tlen[bb]) {
        const float4 bv = *reinterpret_cast<const float4*>(bias + n0 + (tid & 31) * 4);
        float* base = C + (size_t)m0 * N + n0;
#pragma unroll
        for (int it = 0; it < 16; ++it) {
            const int row = it * 8 + (tid >> 5);
            *reinterpret_cast<float4*>(base + (size_t)row * N + (tid & 31) * 4) = bv;
        }
        return;
    }

    const int wave = tid >> 6;
    const int lane = tid & 63;
    const int wm = wave >> 1, wn = wave & 1;   // 2x2 waves -> 64x64 each

    // staging: 16 chunks of 1024B per tile (8 rows x 128B); wave handles 4.
    // lane l -> row c*8 + l/8, col (l%8)*8; lands at LDS chunk base + l*16.
    const int lrow = lane >> 3;
    const int lcol = (lane & 7) * 8;

    f32x4 acc[4][4] = {};

    for (int k0 = 0; k0 < K; k0 += BK) {
#pragma unroll
        for (int i = 0; i < 4; ++i) {
            const int c = wave * 4 + i;
            const int row = c * 8 + lrow;
            const u16* ga = A  + (size_t)(m0 + row) * K + k0 + lcol;
            const u16* gb = Bm + (size_t)(n0 + row) * K + k0 + lcol;
            __builtin_amdgcn_global_load_lds(
                (const __attribute__((address_space(1))) void*)ga,
                (__attribute__((address_space(3))) void*)(lA + c * 512), 16, 0, 0);
            __builtin_amdgcn_global_load_lds(
                (const __attribute__((address_space(1))) void*)gb,
                (__attribute__((address_space(3))) void*)(lB + c * 512), 16, 0, 0);
        }
        __syncthreads();

#pragma unroll
        for (int kt = 0; kt < 2; ++kt) {
            const int ko = kt * 32 + (lane >> 4) * 8;
            bf16x8 af[4], bfv[4];
#pragma unroll
            for (int i = 0; i < 4; ++i) {
                const int ar = wm * 64 + i * 16 + (lane & 15);
                af[i]  = *reinterpret_cast<const bf16x8*>(lA + ar * BK + ko);
                const int br = wn * 64 + i * 16 + (lane & 15);
                bfv[i] = *reinterpret_cast<const bf16x8*>(lB + br * BK + ko);
            }
#pragma unroll
            for (int mi = 0; mi < 4; ++mi)
#pragma unroll
                for (int ni = 0; ni < 4; ++ni)
                    acc[mi][ni] = __builtin_amdgcn_mfma_f32_16x16x32_bf16(
                        af[mi], bfv[ni], acc[mi][ni], 0, 0, 0);
        }
        __syncthreads();
    }

    // epilogue: C/D layout col = lane&15, row = (lane>>4)*4 + reg
    const int cn = lane & 15;
    const int rq = (lane >> 4) * 4;
#pragma unroll
    for (int ni = 0; ni < 4; ++ni) {
        const int gn = n0 + wn * 64 + ni * 16 + cn;
        const float bv = bias[gn];
#pragma unroll
        for (int mi = 0; mi < 4; ++mi) {
            const int gmb = m0 + wm * 64 + mi * 16 + rq;
#pragma unroll
            for (int r = 0; r < 4; ++r)
                C[(size_t)(gmb + r) * N + gn] = acc[mi][ni][r] + bv;
        }
    }
}

// ---------------------------------------------------------------------------
extern "C" void kernel_launch(void* const* d_in, const int* in_sizes, int n_in,
                              void* d_out, int out_size, void* d_ws, size_t ws_size,
                              hipStream_t stream) {
    const float* hidden = (const float*)d_in[0];
    const int*   wid    = (const int*)d_in[1];
    const int*   tlen   = (const int*)d_in[2];
    const float* W      = (const float*)d_in[3];
    const float* bias   = (const float*)d_in[4];
    float* out = (float*)d_out;

    // workspace layout (16B-aligned)
    constexpr size_t POOLED_BYTES = (size_t)M_TOT * H_DIM * 2;   // 25,165,824
    char* ws = (char*)d_ws;
    u16* pooled = (u16*)ws;
    u16* wbf    = (u16*)(ws + POOLED_BYTES);

    pool_or_wconv_kernel<<<POOL_BLOCKS + WCONV_BLOCKS, 256, 0, stream>>>(
        hidden, wid, tlen, W, wbf, pooled);
    gemm_bt_kernel<<<dim3(M_TOT / 128, E_DIM / 128), 256, 0, stream>>>(
        pooled, wbf, bias, tlen, out);
}